// Round 5
// baseline (999.434 us; speedup 1.0000x reference)
//
#include <hip/hip_runtime.h>
#include <math.h>

#define HID 256

typedef __bf16 bf16_t;
typedef __attribute__((ext_vector_type(8))) __bf16 bf16x8;
typedef __attribute__((ext_vector_type(4))) __bf16 bf16x4;
typedef __attribute__((ext_vector_type(4))) float f32x4;

__device__ __forceinline__ float gelu_f(float x){
  return 0.5f * x * (1.0f + erff(x * 0.70710678118654752440f));
}

// ---------------- bf16 MFMA NT GEMM: C = epi(A[M,K] @ Bt[N,K]^T + bias) ----------------
// mode: 0 plain->bf16, 1 relu->bf16, 2 qscale->bf16, 3 skipblend->bf16, 4 sigmoid->f32
// a_f32: A is fp32 (converted to bf16 during LDS staging)
struct GemmDesc {
  const void* A; int lda;
  const bf16_t* Bt; int ldb;
  const float* bias;
  void* C; int ldc;
  int M, N, K;
  int mode, a_gelu, a_f32;
  const float* pvec;
};

template<int NDESC>
__device__ __forceinline__ void mfma_gemm_body(
    const GemmDesc& d,
    const int* __restrict__ a_rows,
    const bf16_t* __restrict__ skipx,
    const float* __restrict__ skip_gate)
{
  constexpr int LDSS = 72;   // 64 + 8 pad (16B) breaks 128B-stride bank aliasing
  __shared__ bf16_t As[128*LDSS];
  __shared__ bf16_t Bs[128*LDSS];
  const int t = threadIdx.x;
  const int wave = t >> 6, lane = t & 63;
  const int quad = lane >> 4, l16 = lane & 15;
  const int row0 = blockIdx.y*128, col0 = blockIdx.x*128;
  if (row0 >= d.M || col0 >= d.N) return;   // block-uniform
  const int R = (wave>>1)*64, Cb = (wave&1)*64;
  f32x4 acc[4][4] = {};

  for (int k0 = 0; k0 < d.K; k0 += 64){
#pragma unroll
    for (int i = 0; i < 4; i++){
      int id = t + i*256;
      int r = id >> 3, c = (id & 7)*8;
      int gr = row0 + r;
      bf16x8 v = {};
      if (gr < d.M){
        int ar = a_rows ? a_rows[gr] : gr;
        if (d.a_f32){
          const float* p = (const float*)d.A + (long long)ar*d.lda + k0 + c;
          float4 f0 = *(const float4*)p;
          float4 f1 = *(const float4*)(p + 4);
          v[0]=(bf16_t)f0.x; v[1]=(bf16_t)f0.y; v[2]=(bf16_t)f0.z; v[3]=(bf16_t)f0.w;
          v[4]=(bf16_t)f1.x; v[5]=(bf16_t)f1.y; v[6]=(bf16_t)f1.z; v[7]=(bf16_t)f1.w;
        } else {
          v = *(const bf16x8*)((const bf16_t*)d.A + (long long)ar*d.lda + k0 + c);
          if (d.a_gelu){
#pragma unroll
            for (int j = 0; j < 8; j++) v[j] = (bf16_t)gelu_f((float)v[j]);
          }
        }
      }
      *(bf16x8*)(As + r*LDSS + c) = v;
    }
#pragma unroll
    for (int i = 0; i < 4; i++){
      int id = t + i*256;
      int r = id >> 3, c = (id & 7)*8;
      int gc = col0 + r;
      bf16x8 v = {};
      if (gc < d.N) v = *(const bf16x8*)(d.Bt + (long long)gc*d.ldb + k0 + c);
      *(bf16x8*)(Bs + r*LDSS + c) = v;
    }
    __syncthreads();
#pragma unroll
    for (int kk = 0; kk < 64; kk += 32){
      bf16x8 af[4], bfr[4];
#pragma unroll
      for (int i = 0; i < 4; i++) af[i]  = *(const bf16x8*)(As + (R  + 16*i + l16)*LDSS + kk + quad*8);
#pragma unroll
      for (int j = 0; j < 4; j++) bfr[j] = *(const bf16x8*)(Bs + (Cb + 16*j + l16)*LDSS + kk + quad*8);
#pragma unroll
      for (int i = 0; i < 4; i++)
#pragma unroll
        for (int j = 0; j < 4; j++)
          acc[i][j] = __builtin_amdgcn_mfma_f32_16x16x32_bf16(af[i], bfr[j], acc[i][j], 0, 0, 0);
    }
    __syncthreads();
  }

  float gate = 0.f;
  if (d.mode == 3) gate = 1.f/(1.f + expf(-(*skip_gate)));
#pragma unroll
  for (int i = 0; i < 4; i++){
#pragma unroll
    for (int j = 0; j < 4; j++){
#pragma unroll
      for (int r = 0; r < 4; r++){
        int gr = row0 + R + 16*i + quad*4 + r;
        int gc = col0 + Cb + 16*j + l16;
        if (gr >= d.M || gc >= d.N) continue;
        float v = acc[i][j][r] + (d.bias ? d.bias[gc] : 0.f);
        if (d.mode == 1) v = fmaxf(v, 0.f);
        else if (d.mode == 2) v *= d.pvec[gc >> 7] * 0.08838834764831845f;
        else if (d.mode == 3) v = gate*v + (1.f - gate)*(float)skipx[(long long)gr*HID + gc];
        if (d.mode == 4) ((float*)d.C)[(long long)gr*d.ldc + gc] = 1.f/(1.f + expf(-v));
        else ((bf16_t*)d.C)[(long long)gr*d.ldc + gc] = (bf16_t)v;
      }
    }
  }
}

__global__ __launch_bounds__(256) void mfma_gemm_k(
    GemmDesc d,
    const int* __restrict__ a_rows,
    const bf16_t* __restrict__ skipx,
    const float* __restrict__ skip_gate)
{
  mfma_gemm_body<1>(d, a_rows, skipx, skip_gate);
}

__global__ __launch_bounds__(256) void mfma_gemm2_k(GemmDesc d0, GemmDesc d1)
{
  if (blockIdx.z == 0) mfma_gemm_body<2>(d0, nullptr, nullptr, nullptr);
  else                 mfma_gemm_body<2>(d1, nullptr, nullptr, nullptr);
}

// ---------------- fused weight transpose+cast: W[K,N](lda) fp32 -> Wt[N,K] bf16 ----------------
struct TW { const float* W; bf16_t* out; int lda; int K; int N; };

__global__ __launch_bounds__(256) void prep_weights_k(TW w0, TW w1, TW w2, TW w3, TW w4){
  TW tw;
  switch (blockIdx.z){
    case 0: tw = w0; break; case 1: tw = w1; break; case 2: tw = w2; break;
    case 3: tw = w3; break; default: tw = w4; break;
  }
  __shared__ float tile[32][33];
  int bx = blockIdx.x*32, by = blockIdx.y*32;
  if (by >= tw.K || bx >= tw.N) return;
  int tx = threadIdx.x, ty = threadIdx.y;
  for (int i = 0; i < 32; i += 8){
    int k = by + ty + i, n = bx + tx;
    tile[ty+i][tx] = (k < tw.K && n < tw.N) ? tw.W[(long long)k*tw.lda + n] : 0.f;
  }
  __syncthreads();
  for (int i = 0; i < 32; i += 8){
    int n = bx + ty + i, k = by + tx;
    if (n < tw.N && k < tw.K) tw.out[(long long)n*tw.K + k] = (bf16_t)tile[tx][ty+i];
  }
}

// ---------------- fold Wk_rel/Wv_rel into kqv_p weights, output transposed bf16 ----------------
__global__ __launch_bounds__(256) void prep_fold_k(
    const float* __restrict__ Wkqv_p, const float* __restrict__ bkqv_p,
    const float* __restrict__ Wk_rel, const float* __restrict__ Wv_rel,
    bf16_t* __restrict__ Wkvt, float* __restrict__ bkv)
{
  int np = blockIdx.x;            // 0..511
  int kv = np >> 8, h = (np >> 7) & 1, n = np & 127;
  int off = kv*512 + h*128;
  const float* rel = (kv ? Wv_rel : Wk_rel) + h*128*128 + n;  // column n, stride 128
  __shared__ float relcol[128];
  int t = threadIdx.x;
  if (t < 128) relcol[t] = rel[t*128];
  __syncthreads();
  int m = t;                      // 0..255
  const float* wp = Wkqv_p + (long long)m*768 + off;
  float acc = 0.f;
#pragma unroll 8
  for (int k = 0; k < 128; k++) acc += wp[k] * relcol[k];
  Wkvt[(long long)np*256 + m] = (bf16_t)acc;
  if (t == 0){
    float b = 0.f;
    for (int k = 0; k < 128; k++) b += bkqv_p[off + k] * relcol[k];
    bkv[np] = b;
  }
}

// ---------------- CSR build ----------------
__global__ void hist_k(const int* __restrict__ dst, int E, int* __restrict__ deg){
  int i = blockIdx.x*256 + threadIdx.x;
  if (i < E) atomicAdd(&deg[dst[i]], 1);
}

__global__ __launch_bounds__(256) void partial_sum_k(
    const int* __restrict__ deg, int n, int* __restrict__ part)
{
  __shared__ int sdata[4];
  int i = blockIdx.x*256 + threadIdx.x;
  int v = (i < n) ? deg[i] : 0;
#pragma unroll
  for (int o = 32; o; o >>= 1) v += __shfl_xor(v, o);
  int lane = threadIdx.x & 63, wid = threadIdx.x >> 6;
  if (lane == 0) sdata[wid] = v;
  __syncthreads();
  if (threadIdx.x == 0) part[blockIdx.x] = sdata[0]+sdata[1]+sdata[2]+sdata[3];
}

__global__ __launch_bounds__(256) void scan_part_k(
    int* __restrict__ part, int nb, int* __restrict__ total_out)
{
  __shared__ int ws[4]; __shared__ int tot;
  int t = threadIdx.x;
  int v = (t < nb) ? part[t] : 0;
  int lane = t & 63, wid = t >> 6;
  int x = v;
#pragma unroll
  for (int o = 1; o < 64; o <<= 1){ int y = __shfl_up(x, o); if (lane >= o) x += y; }
  if (lane == 63) ws[wid] = x;
  __syncthreads();
  if (t == 0){ int s = 0; for (int i = 0; i < 4; i++){ int tmp = ws[i]; ws[i] = s; s += tmp; } tot = s; }
  __syncthreads();
  int excl = x - v + ws[wid];
  if (t < nb) part[t] = excl;
  if (t == 0) *total_out = tot;
}

__global__ __launch_bounds__(256) void scan_offs_k(
    const int* __restrict__ deg, int n, const int* __restrict__ part,
    int* __restrict__ offs, int* __restrict__ cursor)
{
  __shared__ int ws[4];
  int t = threadIdx.x;
  int i = blockIdx.x*256 + t;
  int v = (i < n) ? deg[i] : 0;
  int lane = t & 63, wid = t >> 6;
  int x = v;
#pragma unroll
  for (int o = 1; o < 64; o <<= 1){ int y = __shfl_up(x, o); if (lane >= o) x += y; }
  if (lane == 63) ws[wid] = x;
  __syncthreads();
  int pre = 0;
  for (int k = 0; k < wid; k++) pre += ws[k];
  if (i < n){ int o = part[blockIdx.x] + x - v + pre; offs[i] = o; cursor[i] = o; }
}

__global__ void scatter_k(const int* __restrict__ src, const int* __restrict__ dst, int E,
                          int* __restrict__ cursor, int2* __restrict__ epair){
  int i = blockIdx.x*256 + threadIdx.x;
  if (i < E){
    int s = src[i], d = dst[i];
    int p = atomicAdd(&cursor[d], 1);
    epair[p] = make_int2(s, d);
  }
}

// ---------------- attention phase L: 2 edges/wave, 16 lanes per (edge,head) ----------------
// 16-lane group g (0..3) of the wave handles edge (wave_e0 + (g>>1)), head (g&1);
// lane covers 8 contiguous elems (bf16x8). 4-level shuffle reduce within 16 lanes.
__global__ __launch_bounds__(256) void attn_logit_k(
    const bf16_t* __restrict__ q, const bf16_t* __restrict__ keve,
    const int2* __restrict__ epair, int E, float2* __restrict__ w)
{
  int gid = blockIdx.x*256 + threadIdx.x;
  int e = gid >> 5;                 // 32 threads per edge
  if (e >= E) return;
  int h   = (threadIdx.x >> 4) & 1; // head
  int l16 = threadIdx.x & 15;
  int2 sd = epair[e];
  bf16x8 qv = *(const bf16x8*)(q    + (size_t)sd.y*256 + h*128 + l16*8);
  bf16x8 kv = *(const bf16x8*)(keve + (size_t)sd.x*512 + h*128 + l16*8);
  float p = 0.f;
#pragma unroll
  for (int j = 0; j < 8; j++) p += (float)qv[j]*(float)kv[j];
#pragma unroll
  for (int o = 8; o; o >>= 1) p += __shfl_xor(p, o);   // reduce within 16-lane group
  if (l16 == 0)
    ((float*)w)[(size_t)e*2 + h] = expf(p);
}

// ---------------- attention phase A: 2 dsts/wave, 32 lanes/row, bf16x8 ----------------
__global__ __launch_bounds__(256) void attn_agg_k(
    const bf16_t* __restrict__ keve, const float2* __restrict__ w,
    const int* __restrict__ offs, const int2* __restrict__ epair,
    int Na, bf16_t* __restrict__ agg)
{
  int gid = blockIdx.x*256 + threadIdx.x;
  int dst = gid >> 5, l = gid & 31;   // 32 lanes per dst row
  if (dst >= Na) return;
  int h = l >> 4;                     // lane's 8 elems belong to head h
  int beg = offs[dst], end = offs[dst+1];
  float n[8] = {};
  float den = 0.f;
#pragma unroll 2
  for (int i = beg; i < end; i++){
    float2 wv = w[i];
    float wi = h ? wv.y : wv.x;
    int src = epair[i].x;
    bf16x8 v = *(const bf16x8*)(keve + (size_t)src*512 + 256 + l*8);
#pragma unroll
    for (int j = 0; j < 8; j++) n[j] += wi*(float)v[j];
    den += wi;
  }
  float r = 1.f/(den + 1e-16f);
  bf16x8 o;
#pragma unroll
  for (int j = 0; j < 8; j++) o[j] = (bf16_t)(n[j]*r);
  *(bf16x8*)(agg + (size_t)dst*256 + l*8) = o;
}

extern "C" void kernel_launch(void* const* d_in, const int* in_sizes, int n_in,
                              void* d_out, int out_size, void* d_ws, size_t ws_size,
                              hipStream_t stream)
{
  (void)n_in; (void)out_size; (void)ws_size;
  const float* x_author    = (const float*)d_in[0];
  const float* x_paper     = (const float*)d_in[1];
  const int*   eb_src      = (const int*)d_in[4];
  const int*   eb_dst      = (const int*)d_in[5];
  const int*   input_nodes = (const int*)d_in[6];
  const float* W_in_a  = (const float*)d_in[7];
  const float* b_in_a  = (const float*)d_in[8];
  const float* W_in_p  = (const float*)d_in[9];
  const float* b_in_p  = (const float*)d_in[10];
  const float* Wkqv_a  = (const float*)d_in[11];
  const float* bkqv_a  = (const float*)d_in[12];
  const float* Wkqv_p  = (const float*)d_in[13];
  const float* bkqv_p  = (const float*)d_in[14];
  const float* Wk_rel_b= (const float*)d_in[17];
  const float* Wv_rel_b= (const float*)d_in[18];
  const float* p_b     = (const float*)d_in[20];
  const float* Wout_a  = (const float*)d_in[21];
  const float* bout_a  = (const float*)d_in[22];
  const float* skip_a  = (const float*)d_in[25];
  const float* W_dec   = (const float*)d_in[27];
  const float* b_dec   = (const float*)d_in[28];

  const int Na = in_sizes[0] / 128;
  const int Np = in_sizes[1] / 128;
  const int E  = in_sizes[4];
  const int NI = in_sizes[6];

  char* w = (char*)d_ws;
  auto alloc = [&](size_t bytes)->void*{
    void* p = (void*)w; w += (bytes + 255) & ~(size_t)255; return p;
  };
  bf16_t* xa_bf = (bf16_t*)alloc((size_t)Na*HID*2);
  bf16_t* xp_bf = (bf16_t*)alloc((size_t)Np*HID*2);
  bf16_t* qb    = (bf16_t*)alloc((size_t)Na*HID*2);  // reused as za after attention
  bf16_t* aggb  = (bf16_t*)alloc((size_t)Na*HID*2);
  bf16_t* zin   = (bf16_t*)alloc((size_t)NI*HID*2);
  bf16_t* Wt_in_a = (bf16_t*)alloc(128*HID*2);
  bf16_t* Wt_in_p = (bf16_t*)alloc(128*HID*2);
  bf16_t* Wt_q    = (bf16_t*)alloc(HID*HID*2);
  bf16_t* Wt_out  = (bf16_t*)alloc(HID*HID*2);
  bf16_t* Wt_dec  = (bf16_t*)alloc(HID*HID*2);
  bf16_t* Wkvt    = (bf16_t*)alloc((size_t)512*HID*2);
  float*  bkv     = (float*)alloc(512*4);
  float2* wlog    = (float2*)alloc((size_t)E*8);
  int* deg    = (int*)alloc((size_t)Na*4);
  int* offs   = (int*)alloc((size_t)(Na+1)*4);
  int* cursor = (int*)alloc((size_t)Na*4);
  int* part   = (int*)alloc(1024);
  int2* epair = (int2*)alloc((size_t)E*8);

  // keve [Np,512] bf16 (ke||ve interleaved per row) lives in d_out (51.2 of 102.4 MB),
  // dead before the final GEMM overwrites d_out.
  bf16_t* keve = (bf16_t*)d_out;
  bf16_t* zab  = qb;

  dim3 blk(256);

  // fused weight transposes (fp32 -> bf16, K-major)
  TW tw0 = { W_in_a,       Wt_in_a, 256, 128, 256 };
  TW tw1 = { W_in_p,       Wt_in_p, 256, 128, 256 };
  TW tw2 = { Wkqv_a + 256, Wt_q,    768, 256, 256 };
  TW tw3 = { Wout_a,       Wt_out,  256, 256, 256 };
  TW tw4 = { W_dec,        Wt_dec,  256, 256, 256 };
  prep_weights_k<<<dim3(8,8,5), dim3(32,8), 0, stream>>>(tw0, tw1, tw2, tw3, tw4);
  // fold rel-matrices into kqv_p (transposed bf16 out) + folded bias
  prep_fold_k<<<512, blk, 0, stream>>>(Wkqv_p, bkqv_p, Wk_rel_b, Wv_rel_b, Wkvt, bkv);

  int gyNa = (Na+127)/128, gyNp = (Np+127)/128;
  // batched: xa = relu(x_author @ W_in_a + b) ; xp = relu(x_paper @ W_in_p + b)
  GemmDesc dxa = { x_author, 128, Wt_in_a, 128, b_in_a, xa_bf, HID, Na, 256, 128, 1, 0, 1, nullptr };
  GemmDesc dxp = { x_paper,  128, Wt_in_p, 128, b_in_p, xp_bf, HID, Np, 256, 128, 1, 0, 1, nullptr };
  mfma_gemm2_k<<<dim3(2, gyNa > gyNp ? gyNa : gyNp, 2), blk, 0, stream>>>(dxa, dxp);
  // batched: q = (xa@Wq + b)*p_b/sqrt(128) ; keve = xp @ [Wk||Wv]_fold + [bk||bv]
  GemmDesc dq  = { xa_bf, HID, Wt_q, HID, bkqv_a + 256, qb,   HID, Na, 256, 256, 2, 0, 0, p_b };
  GemmDesc dkv = { xp_bf, HID, Wkvt, HID, bkv,          keve, 512, Np, 512, 256, 0, 0, 0, nullptr };
  mfma_gemm2_k<<<dim3(4, gyNa > gyNp ? gyNa : gyNp, 2), blk, 0, stream>>>(dq, dkv);
  // CSR over edge_b (dst = authors)
  hipMemsetAsync(deg, 0, (size_t)Na*4, stream);
  hist_k<<<(E+255)/256, blk, 0, stream>>>(eb_dst, E, deg);
  int nb = (Na+255)/256;
  partial_sum_k<<<nb, blk, 0, stream>>>(deg, Na, part);
  scan_part_k<<<1, blk, 0, stream>>>(part, nb, offs+Na);
  scan_offs_k<<<nb, blk, 0, stream>>>(deg, Na, part, offs, cursor);
  scatter_k<<<(E+255)/256, blk, 0, stream>>>(eb_src, eb_dst, E, cursor, epair);
  // attention, two barrier-free phases (per-head weights)
  attn_logit_k<<<(E+7)/8, blk, 0, stream>>>(qb, keve, epair, E, wlog);
  attn_agg_k<<<(Na+7)/8, blk, 0, stream>>>(keve, wlog, offs, epair, Na, aggb);
  // za = g*(gelu(agg)@Wout + b) + (1-g)*xa   (za reuses q buffer)
  GemmDesc dza = { aggb, HID, Wt_out, HID, bout_a, zab, HID, Na, 256, 256, 3, 1, 0, nullptr };
  mfma_gemm_k<<<dim3(2, gyNa), blk, 0, stream>>>(dza, nullptr, xa_bf, skip_a);
  // zin = za[input_nodes] @ W_dec + b
  GemmDesc dzi = { zab, HID, Wt_dec, HID, b_dec, zin, HID, NI, 256, 256, 0, 0, 0, nullptr };
  mfma_gemm_k<<<dim3(2, (NI+127)/128), blk, 0, stream>>>(dzi, input_nodes, nullptr, nullptr);
  // out = sigmoid(zin @ za^T)  (fp32 out)
  GemmDesc dfin = { zin, HID, zab, HID, nullptr, (float*)d_out, Na, NI, Na, 256, 4, 0, 0, nullptr };
  mfma_gemm_k<<<dim3((Na+127)/128, (NI+127)/128), blk, 0, stream>>>(dfin, nullptr, nullptr, nullptr);
}